// Round 1
// baseline (4056.656 us; speedup 1.0000x reference)
//
#include <hip/hip_runtime.h>
#include <math.h>

#define N_ATOMS 1000000
#define N_EDGES 4000000
#define N_GRAPHS 1024
#define IN_F 64
#define HID 32
#define LN_EPS 1e-5f

__device__ __forceinline__ float elu_f(float x) {
    return x > 0.0f ? x : expm1f(x);
}

// ---------------- degree + norm ----------------
__global__ __launch_bounds__(256) void deg_kernel(const int* __restrict__ src,
                                                  const int* __restrict__ dst,
                                                  int* __restrict__ deg_out,
                                                  int* __restrict__ deg_in) {
    int e = blockIdx.x * 256 + threadIdx.x;
    if (e < N_EDGES) {
        atomicAdd(&deg_out[src[e]], 1);
        atomicAdd(&deg_in[dst[e]], 1);
    }
}

__global__ __launch_bounds__(256) void norm_kernel(const int* __restrict__ deg_out,
                                                   const int* __restrict__ deg_in,
                                                   float* __restrict__ ns,
                                                   float* __restrict__ nd) {
    int n = blockIdx.x * 256 + threadIdx.x;
    if (n < N_ATOMS) {
        int d0 = deg_out[n], d1 = deg_in[n];
        ns[n] = d0 > 0 ? rsqrtf((float)d0) : 0.0f;
        nd[n] = d1 > 0 ? rsqrtf((float)d1) : 0.0f;
    }
}

// ---------------- input MLP: Linear(64->32) + LN + ELU ----------------
__global__ __launch_bounds__(256) void input_mlp(const float* __restrict__ feats,
                                                 const float* __restrict__ w0,
                                                 const float* __restrict__ b0,
                                                 const float* __restrict__ g0,
                                                 const float* __restrict__ be0,
                                                 float* __restrict__ h) {
    __shared__ float sf[256 * 65];      // feats tile, +1 pad vs 64 stride
    __shared__ float sw[IN_F * HID];    // 8KB weights
    int base = blockIdx.x * 256;
    int tid = threadIdx.x;

    for (int i = tid; i < IN_F * HID; i += 256) sw[i] = w0[i];

    int nrows = min(256, N_ATOMS - base);
    for (int i = tid; i < nrows * IN_F; i += 256) {
        int r = i >> 6, c = i & 63;
        sf[r * 65 + c] = feats[(size_t)base * IN_F + i];
    }
    __syncthreads();
    if (tid >= nrows) return;

    float acc[HID];
#pragma unroll
    for (int j = 0; j < HID; ++j) acc[j] = b0[j];

    const float* frow = &sf[tid * 65];
#pragma unroll 4
    for (int k = 0; k < IN_F; ++k) {
        float f = frow[k];
#pragma unroll
        for (int j = 0; j < HID; ++j) acc[j] += f * sw[k * HID + j];
    }

    float mu = 0.0f;
#pragma unroll
    for (int j = 0; j < HID; ++j) mu += acc[j];
    mu *= (1.0f / HID);
    float var = 0.0f;
#pragma unroll
    for (int j = 0; j < HID; ++j) { float d = acc[j] - mu; var += d * d; }
    var *= (1.0f / HID);
    float rs = rsqrtf(var + LN_EPS);

#pragma unroll
    for (int j = 0; j < HID; ++j)
        acc[j] = elu_f((acc[j] - mu) * rs * g0[j] + be0[j]);

    float4* hv = (float4*)&h[(size_t)(base + tid) * HID];
#pragma unroll
    for (int q = 0; q < HID / 4; ++q)
        hv[q] = make_float4(acc[4 * q], acc[4 * q + 1], acc[4 * q + 2], acc[4 * q + 3]);
}

// ---------------- edge gather/scatter: m[dst] += h[src]*ns[src] ----------------
// 8 threads per edge, each handles a float4 chunk of the 32-wide row.
__global__ __launch_bounds__(256) void gather_scatter(const float* __restrict__ h,
                                                      const float* __restrict__ ns,
                                                      const int* __restrict__ src,
                                                      const int* __restrict__ dst,
                                                      float* __restrict__ m) {
    long long t = (long long)blockIdx.x * 256 + threadIdx.x;
    int e = (int)(t >> 3);
    if (e >= N_EDGES) return;
    int c = ((int)t & 7) * 4;
    int s = src[e], d = dst[e];
    float sc = ns[s];
    float4 v = *(const float4*)&h[(size_t)s * HID + c];
    float* mp = &m[(size_t)d * HID + c];
    atomicAdd(mp + 0, v.x * sc);
    atomicAdd(mp + 1, v.y * sc);
    atomicAdd(mp + 2, v.z * sc);
    atomicAdd(mp + 3, v.w * sc);
}

// ---------------- fused: (m*nd)@wc+bc -> ELU -> @w+b -> LN -> ELU ----------------
__global__ __launch_bounds__(256) void node_update(const float* __restrict__ m,
                                                   const float* __restrict__ nd,
                                                   const float* __restrict__ wc,
                                                   const float* __restrict__ bc,
                                                   const float* __restrict__ w,
                                                   const float* __restrict__ b,
                                                   const float* __restrict__ g,
                                                   const float* __restrict__ be,
                                                   float* __restrict__ h) {
    __shared__ float sm[256 * 33];     // m tile, +1 pad
    __shared__ float swc[HID * HID];
    __shared__ float sw[HID * HID];
    int base = blockIdx.x * 256;
    int tid = threadIdx.x;

    for (int i = tid; i < HID * HID; i += 256) { swc[i] = wc[i]; sw[i] = w[i]; }

    int nrows = min(256, N_ATOMS - base);
    for (int i = tid; i < nrows * HID; i += 256) {
        int r = i >> 5, c = i & 31;
        sm[r * 33 + c] = m[(size_t)base * HID + i];
    }
    __syncthreads();
    if (tid >= nrows) return;

    int node = base + tid;
    float scale = nd[node];
    const float* mr = &sm[tid * 33];

    float t1[HID];
#pragma unroll
    for (int j = 0; j < HID; ++j) t1[j] = bc[j];
#pragma unroll 4
    for (int k = 0; k < HID; ++k) {
        float f = mr[k] * scale;
#pragma unroll
        for (int j = 0; j < HID; ++j) t1[j] += f * swc[k * HID + j];
    }
#pragma unroll
    for (int j = 0; j < HID; ++j) t1[j] = elu_f(t1[j]);

    float t2[HID];
#pragma unroll
    for (int j = 0; j < HID; ++j) t2[j] = b[j];
#pragma unroll 4
    for (int k = 0; k < HID; ++k) {
        float f = t1[k];
#pragma unroll
        for (int j = 0; j < HID; ++j) t2[j] += f * sw[k * HID + j];
    }

    float mu = 0.0f;
#pragma unroll
    for (int j = 0; j < HID; ++j) mu += t2[j];
    mu *= (1.0f / HID);
    float var = 0.0f;
#pragma unroll
    for (int j = 0; j < HID; ++j) { float d = t2[j] - mu; var += d * d; }
    var *= (1.0f / HID);
    float rs = rsqrtf(var + LN_EPS);

#pragma unroll
    for (int j = 0; j < HID; ++j)
        t2[j] = elu_f((t2[j] - mu) * rs * g[j] + be[j]);

    float4* hv = (float4*)&h[(size_t)node * HID];
#pragma unroll
    for (int q = 0; q < HID / 4; ++q)
        hv[q] = make_float4(t2[4 * q], t2[4 * q + 1], t2[4 * q + 2], t2[4 * q + 3]);
}

// ---------------- output head + per-graph readout (gid is sorted) ----------------
__global__ __launch_bounds__(256) void readout(const float* __restrict__ h,
                                               const int* __restrict__ gid,
                                               const float* __restrict__ wout,
                                               const float* __restrict__ bout,
                                               float* __restrict__ out) {
    __shared__ float swout[HID];
    __shared__ float buckets[N_GRAPHS];
    __shared__ int s_gf, s_range;
    int base = blockIdx.x * 256;
    int tid = threadIdx.x;
    int nrows = min(256, N_ATOMS - base);

    if (tid < HID) swout[tid] = wout[tid];
    if (tid == 0) {
        int gf = gid[base];
        int gl = gid[base + nrows - 1];
        s_gf = gf;
        s_range = gl - gf + 1;
    }
    __syncthreads();
    int gf = s_gf, range = s_range;
    for (int i = tid; i < range; i += 256) buckets[i] = 0.0f;
    __syncthreads();

    if (tid < nrows) {
        int node = base + tid;
        const float4* hv = (const float4*)&h[(size_t)node * HID];
        float acc = bout[0];
#pragma unroll
        for (int q = 0; q < 8; ++q) {
            float4 v = hv[q];
            acc += v.x * swout[4 * q] + v.y * swout[4 * q + 1] +
                   v.z * swout[4 * q + 2] + v.w * swout[4 * q + 3];
        }
        acc = elu_f(acc);
        atomicAdd(&buckets[gid[node] - gf], acc);
    }
    __syncthreads();
    for (int i = tid; i < range; i += 256) {
        float v = buckets[i];
        if (v != 0.0f) atomicAdd(&out[gf + i], v);
    }
}

extern "C" void kernel_launch(void* const* d_in, const int* in_sizes, int n_in,
                              void* d_out, int out_size, void* d_ws, size_t ws_size,
                              hipStream_t stream) {
    const float* feats = (const float*)d_in[0];
    const int* src = (const int*)d_in[1];
    const int* dst = (const int*)d_in[2];
    const int* gid = (const int*)d_in[3];
    const float* w0  = (const float*)d_in[4];
    const float* b0  = (const float*)d_in[5];
    const float* g0  = (const float*)d_in[6];
    const float* be0 = (const float*)d_in[7];
    const float* wc1 = (const float*)d_in[8];
    const float* bc1 = (const float*)d_in[9];
    const float* w1  = (const float*)d_in[10];
    const float* b1  = (const float*)d_in[11];
    const float* g1  = (const float*)d_in[12];
    const float* be1 = (const float*)d_in[13];
    const float* wc2 = (const float*)d_in[14];
    const float* bc2 = (const float*)d_in[15];
    const float* w2  = (const float*)d_in[16];
    const float* b2  = (const float*)d_in[17];
    const float* g2  = (const float*)d_in[18];
    const float* be2 = (const float*)d_in[19];
    const float* wout = (const float*)d_in[20];
    const float* bout = (const float*)d_in[21];
    float* out = (float*)d_out;

    // workspace layout (272 MB total)
    char* ws = (char*)d_ws;
    const size_t HBYTES = (size_t)N_ATOMS * HID * sizeof(float);  // 128 MB
    float* h    = (float*)(ws);
    float* m    = (float*)(ws + HBYTES);
    float* ns   = (float*)(ws + 2 * HBYTES);
    float* nd   = (float*)(ws + 2 * HBYTES + 4000000);
    int* deg_o  = (int*)(ws + 2 * HBYTES + 8000000);
    int* deg_i  = (int*)(ws + 2 * HBYTES + 12000000);

    hipMemsetAsync(deg_o, 0, 2 * (size_t)N_ATOMS * sizeof(int), stream);
    hipMemsetAsync(out, 0, (size_t)N_GRAPHS * sizeof(float), stream);

    deg_kernel<<<(N_EDGES + 255) / 256, 256, 0, stream>>>(src, dst, deg_o, deg_i);
    norm_kernel<<<(N_ATOMS + 255) / 256, 256, 0, stream>>>(deg_o, deg_i, ns, nd);

    int nblocks = (N_ATOMS + 255) / 256;  // 3907
    input_mlp<<<nblocks, 256, 0, stream>>>(feats, w0, b0, g0, be0, h);

    const float* WC[2] = {wc1, wc2};
    const float* BC[2] = {bc1, bc2};
    const float* W[2]  = {w1, w2};
    const float* B[2]  = {b1, b2};
    const float* Gm[2] = {g1, g2};
    const float* BE[2] = {be1, be2};

    long long egrid = ((long long)N_EDGES * 8 + 255) / 256;  // 125000 blocks
    for (int blk = 0; blk < 2; ++blk) {
        hipMemsetAsync(m, 0, HBYTES, stream);
        gather_scatter<<<(int)egrid, 256, 0, stream>>>(h, ns, src, dst, m);
        node_update<<<nblocks, 256, 0, stream>>>(m, nd, WC[blk], BC[blk], W[blk], B[blk],
                                                 Gm[blk], BE[blk], h);
    }

    readout<<<nblocks, 256, 0, stream>>>(h, gid, wout, bout, out);
}

// Round 2
// 1005.424 us; speedup vs baseline: 4.0348x; 4.0348x over previous
//
#include <hip/hip_runtime.h>
#include <math.h>

#define N_ATOMS 1000000
#define N_EDGES 4000000
#define N_GRAPHS 1024
#define IN_F 64
#define HID 32
#define LN_EPS 1e-5f
#define SCAN_NB 977   // ceil(1e6 / 1024)

typedef unsigned int uint;
typedef unsigned short ushort;

__device__ __forceinline__ float elu_f(float x) {
    return x > 0.0f ? x : expm1f(x);
}
__device__ __forceinline__ uint f2bf(float x) {   // fp32 -> bf16 bits, RNE
    uint u = __float_as_uint(x);
    return (u + 0x7fffu + ((u >> 16) & 1u)) >> 16;
}

// ---------------- degree ----------------
__global__ __launch_bounds__(256) void deg_kernel(const int* __restrict__ src,
                                                  const int* __restrict__ dst,
                                                  int* __restrict__ deg_out,
                                                  int* __restrict__ deg_in) {
    int e = blockIdx.x * 256 + threadIdx.x;
    if (e < N_EDGES) {
        atomicAdd(&deg_out[src[e]], 1);
        atomicAdd(&deg_in[dst[e]], 1);
    }
}

__global__ __launch_bounds__(256) void norm_kernel(const int* __restrict__ deg_out,
                                                   const int* __restrict__ deg_in,
                                                   float* __restrict__ ns,
                                                   float* __restrict__ nd) {
    int n = blockIdx.x * 256 + threadIdx.x;
    if (n < N_ATOMS) {
        int d0 = deg_out[n], d1 = deg_in[n];
        ns[n] = d0 > 0 ? rsqrtf((float)d0) : 0.0f;
        nd[n] = d1 > 0 ? rsqrtf((float)d1) : 0.0f;
    }
}

// ---------------- exclusive scan of deg_in (1024 elems / block) ----------------
__global__ __launch_bounds__(256) void scan_a(const int* __restrict__ deg,
                                              int* __restrict__ offs,
                                              int* __restrict__ bsum) {
    __shared__ int lds[256];
    int base = blockIdx.x * 1024;
    int tid = threadIdx.x;
    int v[4]; int sum = 0;
#pragma unroll
    for (int q = 0; q < 4; ++q) {
        int idx = base + tid * 4 + q;
        v[q] = (idx < N_ATOMS) ? deg[idx] : 0;
        sum += v[q];
    }
    lds[tid] = sum;
    __syncthreads();
    for (int off = 1; off < 256; off <<= 1) {
        int t = (tid >= off) ? lds[tid - off] : 0;
        __syncthreads();
        lds[tid] += t;
        __syncthreads();
    }
    int excl = (tid > 0) ? lds[tid - 1] : 0;
    if (tid == 255) bsum[blockIdx.x] = lds[255];
    int run = excl;
#pragma unroll
    for (int q = 0; q < 4; ++q) {
        int idx = base + tid * 4 + q;
        if (idx < N_ATOMS) offs[idx] = run;
        run += v[q];
    }
}

__global__ __launch_bounds__(1024) void scan_b(int* __restrict__ bsum) {
    __shared__ int lds[1024];
    int tid = threadIdx.x;
    lds[tid] = (tid < SCAN_NB) ? bsum[tid] : 0;
    __syncthreads();
    for (int off = 1; off < 1024; off <<= 1) {
        int t = (tid >= off) ? lds[tid - off] : 0;
        __syncthreads();
        lds[tid] += t;
        __syncthreads();
    }
    if (tid < SCAN_NB) bsum[tid] = (tid > 0) ? lds[tid - 1] : 0;
}

__global__ __launch_bounds__(256) void scan_c(int* __restrict__ offs,
                                              const int* __restrict__ bsum) {
    int base = blockIdx.x * 1024;
    int add = bsum[blockIdx.x];
    for (int i = threadIdx.x; i < 1024; i += 256) {
        int idx = base + i;
        if (idx < N_ATOMS) offs[idx] += add;
    }
    if (blockIdx.x == 0 && threadIdx.x == 0) offs[N_ATOMS] = N_EDGES;
}

// ---------------- CSR fill: edges grouped by dst, record = (src, ns[src]) ----------------
__global__ __launch_bounds__(256) void fill_csr(const int* __restrict__ src,
                                                const int* __restrict__ dst,
                                                const float* __restrict__ ns,
                                                const int* __restrict__ offs,
                                                int* __restrict__ cursor,
                                                uint2* __restrict__ edges) {
    int e = blockIdx.x * 256 + threadIdx.x;
    if (e >= N_EDGES) return;
    int d = dst[e];
    int p = atomicAdd(&cursor[d], 1);
    int s = src[e];
    edges[offs[d] + p] = make_uint2((uint)s, __float_as_uint(ns[s]));
}

// ---------------- input MLP: Linear(64->32) + LN + ELU -> bf16 h ----------------
__global__ __launch_bounds__(256) void input_mlp(const float* __restrict__ feats,
                                                 const float* __restrict__ w0,
                                                 const float* __restrict__ b0,
                                                 const float* __restrict__ g0,
                                                 const float* __restrict__ be0,
                                                 ushort* __restrict__ h) {
    __shared__ float sf[256 * 65];
    __shared__ float sw[IN_F * HID];
    int base = blockIdx.x * 256;
    int tid = threadIdx.x;

    for (int i = tid; i < IN_F * HID; i += 256) sw[i] = w0[i];

    int nrows = min(256, N_ATOMS - base);
    for (int i = tid; i < nrows * IN_F; i += 256) {
        int r = i >> 6, c = i & 63;
        sf[r * 65 + c] = feats[(size_t)base * IN_F + i];
    }
    __syncthreads();
    if (tid >= nrows) return;

    float acc[HID];
#pragma unroll
    for (int j = 0; j < HID; ++j) acc[j] = b0[j];

    const float* frow = &sf[tid * 65];
#pragma unroll 4
    for (int k = 0; k < IN_F; ++k) {
        float f = frow[k];
#pragma unroll
        for (int j = 0; j < HID; ++j) acc[j] += f * sw[k * HID + j];
    }

    float mu = 0.0f;
#pragma unroll
    for (int j = 0; j < HID; ++j) mu += acc[j];
    mu *= (1.0f / HID);
    float var = 0.0f;
#pragma unroll
    for (int j = 0; j < HID; ++j) { float d = acc[j] - mu; var += d * d; }
    var *= (1.0f / HID);
    float rs = rsqrtf(var + LN_EPS);

#pragma unroll
    for (int j = 0; j < HID; ++j)
        acc[j] = elu_f((acc[j] - mu) * rs * g0[j] + be0[j]);

    uint words[HID / 2];
#pragma unroll
    for (int q = 0; q < HID / 2; ++q)
        words[q] = f2bf(acc[2 * q]) | (f2bf(acc[2 * q + 1]) << 16);
    uint4* hv = (uint4*)&h[(size_t)(base + tid) * HID];
#pragma unroll
    for (int q = 0; q < 4; ++q)
        hv[q] = make_uint4(words[4 * q], words[4 * q + 1], words[4 * q + 2], words[4 * q + 3]);
}

// ---- fused GraphConv + node MLP: pull-gather (no atomics) + 2 matmuls + LN ----
__global__ __launch_bounds__(256) void conv_node(const ushort* __restrict__ hin,
                                                 const int* __restrict__ offs,
                                                 const uint2* __restrict__ edges,
                                                 const float* __restrict__ nd,
                                                 const float* __restrict__ wc,
                                                 const float* __restrict__ bc,
                                                 const float* __restrict__ w,
                                                 const float* __restrict__ b,
                                                 const float* __restrict__ g,
                                                 const float* __restrict__ be,
                                                 ushort* __restrict__ hout) {
    __shared__ float swc[HID * HID];
    __shared__ float sw[HID * HID];
    int tid = threadIdx.x;
    for (int i = tid; i < HID * HID; i += 256) { swc[i] = wc[i]; sw[i] = w[i]; }
    __syncthreads();

    int node = blockIdx.x * 256 + tid;
    if (node >= N_ATOMS) return;

    int s0 = offs[node], s1 = offs[node + 1];
    float acc[HID];
#pragma unroll
    for (int j = 0; j < HID; ++j) acc[j] = 0.0f;

    for (int i = s0; i < s1; ++i) {
        uint2 ed = edges[i];
        float wt = __uint_as_float(ed.y);
        const uint4* hr = (const uint4*)(hin + (size_t)ed.x * HID);
#pragma unroll
        for (int q = 0; q < 4; ++q) {
            uint4 u = hr[q];
            uint vv[4] = {u.x, u.y, u.z, u.w};
#pragma unroll
            for (int r = 0; r < 4; ++r) {
                float lo = __uint_as_float(vv[r] << 16);
                float hi = __uint_as_float(vv[r] & 0xffff0000u);
                acc[q * 8 + r * 2]     += lo * wt;
                acc[q * 8 + r * 2 + 1] += hi * wt;
            }
        }
    }

    float scale = nd[node];
    float t1[HID];
#pragma unroll
    for (int j = 0; j < HID; ++j) t1[j] = bc[j];
#pragma unroll 4
    for (int k = 0; k < HID; ++k) {
        float f = acc[k] * scale;
#pragma unroll
        for (int j = 0; j < HID; ++j) t1[j] += f * swc[k * HID + j];
    }
#pragma unroll
    for (int j = 0; j < HID; ++j) t1[j] = elu_f(t1[j]);

    float t2[HID];
#pragma unroll
    for (int j = 0; j < HID; ++j) t2[j] = b[j];
#pragma unroll 4
    for (int k = 0; k < HID; ++k) {
        float f = t1[k];
#pragma unroll
        for (int j = 0; j < HID; ++j) t2[j] += f * sw[k * HID + j];
    }

    float mu = 0.0f;
#pragma unroll
    for (int j = 0; j < HID; ++j) mu += t2[j];
    mu *= (1.0f / HID);
    float var = 0.0f;
#pragma unroll
    for (int j = 0; j < HID; ++j) { float d = t2[j] - mu; var += d * d; }
    var *= (1.0f / HID);
    float rs = rsqrtf(var + LN_EPS);

#pragma unroll
    for (int j = 0; j < HID; ++j)
        t2[j] = elu_f((t2[j] - mu) * rs * g[j] + be[j]);

    uint words[HID / 2];
#pragma unroll
    for (int q = 0; q < HID / 2; ++q)
        words[q] = f2bf(t2[2 * q]) | (f2bf(t2[2 * q + 1]) << 16);
    uint4* hv = (uint4*)&hout[(size_t)node * HID];
#pragma unroll
    for (int q = 0; q < 4; ++q)
        hv[q] = make_uint4(words[4 * q], words[4 * q + 1], words[4 * q + 2], words[4 * q + 3]);
}

// ---------------- output head + per-graph readout (gid sorted) ----------------
__global__ __launch_bounds__(256) void readout(const ushort* __restrict__ h,
                                               const int* __restrict__ gid,
                                               const float* __restrict__ wout,
                                               const float* __restrict__ bout,
                                               float* __restrict__ out) {
    __shared__ float swout[HID];
    __shared__ float buckets[N_GRAPHS];
    __shared__ int s_gf, s_range;
    int base = blockIdx.x * 256;
    int tid = threadIdx.x;
    int nrows = min(256, N_ATOMS - base);

    if (tid < HID) swout[tid] = wout[tid];
    if (tid == 0) {
        int gf = gid[base];
        int gl = gid[base + nrows - 1];
        s_gf = gf;
        s_range = gl - gf + 1;
    }
    __syncthreads();
    int gf = s_gf, range = s_range;
    for (int i = tid; i < range; i += 256) buckets[i] = 0.0f;
    __syncthreads();

    if (tid < nrows) {
        int node = base + tid;
        const uint4* hv = (const uint4*)&h[(size_t)node * HID];
        float acc = bout[0];
#pragma unroll
        for (int q = 0; q < 4; ++q) {
            uint4 u = hv[q];
            uint vv[4] = {u.x, u.y, u.z, u.w};
#pragma unroll
            for (int r = 0; r < 4; ++r) {
                float lo = __uint_as_float(vv[r] << 16);
                float hi = __uint_as_float(vv[r] & 0xffff0000u);
                acc += lo * swout[q * 8 + r * 2] + hi * swout[q * 8 + r * 2 + 1];
            }
        }
        acc = elu_f(acc);
        atomicAdd(&buckets[gid[node] - gf], acc);
    }
    __syncthreads();
    for (int i = tid; i < range; i += 256) {
        float v = buckets[i];
        if (v != 0.0f) atomicAdd(&out[gf + i], v);
    }
}

extern "C" void kernel_launch(void* const* d_in, const int* in_sizes, int n_in,
                              void* d_out, int out_size, void* d_ws, size_t ws_size,
                              hipStream_t stream) {
    const float* feats = (const float*)d_in[0];
    const int* src = (const int*)d_in[1];
    const int* dst = (const int*)d_in[2];
    const int* gid = (const int*)d_in[3];
    const float* w0  = (const float*)d_in[4];
    const float* b0  = (const float*)d_in[5];
    const float* g0  = (const float*)d_in[6];
    const float* be0 = (const float*)d_in[7];
    const float* wc1 = (const float*)d_in[8];
    const float* bc1 = (const float*)d_in[9];
    const float* w1  = (const float*)d_in[10];
    const float* b1  = (const float*)d_in[11];
    const float* g1  = (const float*)d_in[12];
    const float* be1 = (const float*)d_in[13];
    const float* wc2 = (const float*)d_in[14];
    const float* bc2 = (const float*)d_in[15];
    const float* w2  = (const float*)d_in[16];
    const float* b2  = (const float*)d_in[17];
    const float* g2  = (const float*)d_in[18];
    const float* be2 = (const float*)d_in[19];
    const float* wout = (const float*)d_in[20];
    const float* bout = (const float*)d_in[21];
    float* out = (float*)d_out;

    // workspace layout (~184 MB)
    char* ws = (char*)d_ws;
    ushort* h0  = (ushort*)(ws + 0);           // 64,000,000 B
    ushort* h1  = (ushort*)(ws + 64000000);    // 64,000,000 B
    int* offs   = (int*)(ws + 128000000);      // 4,000,004 B (N+1)
    uint2* edges = (uint2*)(ws + 132000064);   // 32,000,000 B
    float* ns   = (float*)(ws + 164000064);    // 4,000,000 B
    float* nd   = (float*)(ws + 168000064);    // 4,000,000 B
    int* deg_o  = (int*)(ws + 172000064);      // 4,000,000 B
    int* deg_i  = (int*)(ws + 176000064);      // 4,000,000 B
    int* cursor = (int*)(ws + 180000064);      // 4,000,000 B
    int* bsum   = (int*)(ws + 184000064);      // 4,096 B

    hipMemsetAsync(deg_o, 0, 2 * (size_t)N_ATOMS * sizeof(int), stream);  // deg_o + deg_i
    hipMemsetAsync(cursor, 0, (size_t)N_ATOMS * sizeof(int), stream);
    hipMemsetAsync(out, 0, (size_t)N_GRAPHS * sizeof(float), stream);

    int eb = (N_EDGES + 255) / 256;   // 15625
    int nb = (N_ATOMS + 255) / 256;   // 3907

    deg_kernel<<<eb, 256, 0, stream>>>(src, dst, deg_o, deg_i);
    norm_kernel<<<nb, 256, 0, stream>>>(deg_o, deg_i, ns, nd);
    scan_a<<<SCAN_NB, 256, 0, stream>>>(deg_i, offs, bsum);
    scan_b<<<1, 1024, 0, stream>>>(bsum);
    scan_c<<<SCAN_NB, 256, 0, stream>>>(offs, bsum);
    fill_csr<<<eb, 256, 0, stream>>>(src, dst, ns, offs, cursor, edges);

    input_mlp<<<nb, 256, 0, stream>>>(feats, w0, b0, g0, be0, h0);

    conv_node<<<nb, 256, 0, stream>>>(h0, offs, edges, nd, wc1, bc1, w1, b1, g1, be1, h1);
    conv_node<<<nb, 256, 0, stream>>>(h1, offs, edges, nd, wc2, bc2, w2, b2, g2, be2, h0);

    readout<<<nb, 256, 0, stream>>>(h0, gid, wout, bout, out);
}

// Round 3
// 950.682 us; speedup vs baseline: 4.2671x; 1.0576x over previous
//
#include <hip/hip_runtime.h>
#include <math.h>

#define N_ATOMS 1000000
#define N_EDGES 4000000
#define N_GRAPHS 1024
#define IN_F 64
#define HID 32
#define LN_EPS 1e-5f
#define SCAN_NB 977   // ceil(1e6 / 1024)

typedef unsigned int uint;
typedef unsigned short ushort;

__device__ __forceinline__ float elu_f(float x) {
    return x > 0.0f ? x : expm1f(x);
}
__device__ __forceinline__ uint f2bf(float x) {   // fp32 -> bf16 bits, RNE
    uint u = __float_as_uint(x);
    return (u + 0x7fffu + ((u >> 16) & 1u)) >> 16;
}

// ------- degree histograms + per-edge rank (rank = position within dst bucket) -------
__global__ __launch_bounds__(256) void deg_rank(const int* __restrict__ src,
                                                const int* __restrict__ dst,
                                                int* __restrict__ deg_out,
                                                int* __restrict__ deg_in,
                                                int* __restrict__ rank) {
    int t = blockIdx.x * 256 + threadIdx.x;
    int e4 = t * 4;
    if (e4 + 3 < N_EDGES) {
        int4 s = *(const int4*)&src[e4];
        int4 d = *(const int4*)&dst[e4];
        atomicAdd(&deg_out[s.x], 1);
        atomicAdd(&deg_out[s.y], 1);
        atomicAdd(&deg_out[s.z], 1);
        atomicAdd(&deg_out[s.w], 1);
        int4 r;
        r.x = atomicAdd(&deg_in[d.x], 1);
        r.y = atomicAdd(&deg_in[d.y], 1);
        r.z = atomicAdd(&deg_in[d.z], 1);
        r.w = atomicAdd(&deg_in[d.w], 1);
        *(int4*)&rank[e4] = r;
    } else {
        for (int e = e4; e < N_EDGES; ++e) {
            atomicAdd(&deg_out[src[e]], 1);
            rank[e] = atomicAdd(&deg_in[dst[e]], 1);
        }
    }
}

__global__ __launch_bounds__(256) void norm_kernel(const int* __restrict__ deg_out,
                                                   const int* __restrict__ deg_in,
                                                   float* __restrict__ ns,
                                                   float* __restrict__ nd) {
    int n = blockIdx.x * 256 + threadIdx.x;
    if (n < N_ATOMS) {
        int d0 = deg_out[n], d1 = deg_in[n];
        ns[n] = d0 > 0 ? rsqrtf((float)d0) : 0.0f;
        nd[n] = d1 > 0 ? rsqrtf((float)d1) : 0.0f;
    }
}

// ---------------- exclusive scan of deg_in (1024 elems / block) ----------------
__global__ __launch_bounds__(256) void scan_a(const int* __restrict__ deg,
                                              int* __restrict__ offs,
                                              int* __restrict__ bsum) {
    __shared__ int lds[256];
    int base = blockIdx.x * 1024;
    int tid = threadIdx.x;
    int v[4]; int sum = 0;
#pragma unroll
    for (int q = 0; q < 4; ++q) {
        int idx = base + tid * 4 + q;
        v[q] = (idx < N_ATOMS) ? deg[idx] : 0;
        sum += v[q];
    }
    lds[tid] = sum;
    __syncthreads();
    for (int off = 1; off < 256; off <<= 1) {
        int t = (tid >= off) ? lds[tid - off] : 0;
        __syncthreads();
        lds[tid] += t;
        __syncthreads();
    }
    int excl = (tid > 0) ? lds[tid - 1] : 0;
    if (tid == 255) bsum[blockIdx.x] = lds[255];
    int run = excl;
#pragma unroll
    for (int q = 0; q < 4; ++q) {
        int idx = base + tid * 4 + q;
        if (idx < N_ATOMS) offs[idx] = run;
        run += v[q];
    }
}

__global__ __launch_bounds__(1024) void scan_b(int* __restrict__ bsum) {
    __shared__ int lds[1024];
    int tid = threadIdx.x;
    lds[tid] = (tid < SCAN_NB) ? bsum[tid] : 0;
    __syncthreads();
    for (int off = 1; off < 1024; off <<= 1) {
        int t = (tid >= off) ? lds[tid - off] : 0;
        __syncthreads();
        lds[tid] += t;
        __syncthreads();
    }
    if (tid < SCAN_NB) bsum[tid] = (tid > 0) ? lds[tid - 1] : 0;
}

__global__ __launch_bounds__(256) void scan_c(int* __restrict__ offs,
                                              const int* __restrict__ bsum) {
    int base = blockIdx.x * 1024;
    int add = bsum[blockIdx.x];
    for (int i = threadIdx.x; i < 1024; i += 256) {
        int idx = base + i;
        if (idx < N_ATOMS) offs[idx] += add;
    }
    if (blockIdx.x == 0 && threadIdx.x == 0) offs[N_ATOMS] = N_EDGES;
}

// ------- CSR fill, atomic-free: eidx[offs[dst] + rank] = src -------
__global__ __launch_bounds__(256) void fill_csr(const int* __restrict__ src,
                                                const int* __restrict__ dst,
                                                const int* __restrict__ rank,
                                                const int* __restrict__ offs,
                                                int* __restrict__ eidx) {
    int e = blockIdx.x * 256 + threadIdx.x;
    if (e >= N_EDGES) return;
    eidx[offs[dst[e]] + rank[e]] = src[e];
}

// ------- input MLP: Linear(64->32) + LN + ELU, output prescaled by ns -> bf16 -------
__global__ __launch_bounds__(256) void input_mlp(const float* __restrict__ feats,
                                                 const float* __restrict__ w0,
                                                 const float* __restrict__ b0,
                                                 const float* __restrict__ g0,
                                                 const float* __restrict__ be0,
                                                 const float* __restrict__ ns,
                                                 ushort* __restrict__ hs) {
    __shared__ float sf[256 * 65];
    __shared__ float sw[IN_F * HID];
    int base = blockIdx.x * 256;
    int tid = threadIdx.x;

    for (int i = tid; i < IN_F * HID; i += 256) sw[i] = w0[i];

    int nrows = min(256, N_ATOMS - base);
    for (int i = tid; i < nrows * IN_F; i += 256) {
        int r = i >> 6, c = i & 63;
        sf[r * 65 + c] = feats[(size_t)base * IN_F + i];
    }
    __syncthreads();
    if (tid >= nrows) return;

    float acc[HID];
#pragma unroll
    for (int j = 0; j < HID; ++j) acc[j] = b0[j];

    const float* frow = &sf[tid * 65];
#pragma unroll 4
    for (int k = 0; k < IN_F; ++k) {
        float f = frow[k];
#pragma unroll
        for (int j = 0; j < HID; ++j) acc[j] += f * sw[k * HID + j];
    }

    float mu = 0.0f;
#pragma unroll
    for (int j = 0; j < HID; ++j) mu += acc[j];
    mu *= (1.0f / HID);
    float var = 0.0f;
#pragma unroll
    for (int j = 0; j < HID; ++j) { float d = acc[j] - mu; var += d * d; }
    var *= (1.0f / HID);
    float rs = rsqrtf(var + LN_EPS);

    float os = ns[base + tid];
#pragma unroll
    for (int j = 0; j < HID; ++j)
        acc[j] = elu_f((acc[j] - mu) * rs * g0[j] + be0[j]) * os;

    uint words[HID / 2];
#pragma unroll
    for (int q = 0; q < HID / 2; ++q)
        words[q] = f2bf(acc[2 * q]) | (f2bf(acc[2 * q + 1]) << 16);
    uint4* hv = (uint4*)&hs[(size_t)(base + tid) * HID];
#pragma unroll
    for (int q = 0; q < 4; ++q)
        hv[q] = make_uint4(words[4 * q], words[4 * q + 1], words[4 * q + 2], words[4 * q + 3]);
}

// ---- fused GraphConv + node MLP: pull row-sum (inputs pre-scaled by ns) ----
// out = elu(LN(elu((sum * nd) @ wc + bc) @ w + b)); stored * ns_out (or plain if null)
__global__ __launch_bounds__(256) void conv_node(const ushort* __restrict__ hin,
                                                 const int* __restrict__ offs,
                                                 const int* __restrict__ eidx,
                                                 const float* __restrict__ nd,
                                                 const float* __restrict__ wc,
                                                 const float* __restrict__ bc,
                                                 const float* __restrict__ w,
                                                 const float* __restrict__ b,
                                                 const float* __restrict__ g,
                                                 const float* __restrict__ be,
                                                 const float* __restrict__ ns_out,
                                                 ushort* __restrict__ hout) {
    __shared__ float swc[HID * HID];
    __shared__ float sw[HID * HID];
    int tid = threadIdx.x;
    for (int i = tid; i < HID * HID; i += 256) { swc[i] = wc[i]; sw[i] = w[i]; }
    __syncthreads();

    int node = blockIdx.x * 256 + tid;
    if (node >= N_ATOMS) return;

    int s0 = offs[node], s1 = offs[node + 1];
    float acc[HID];
#pragma unroll
    for (int j = 0; j < HID; ++j) acc[j] = 0.0f;

    for (int i = s0; i < s1; ++i) {
        int s = eidx[i];
        const uint4* hr = (const uint4*)(hin + (size_t)s * HID);
#pragma unroll
        for (int q = 0; q < 4; ++q) {
            uint4 u = hr[q];
            uint vv[4] = {u.x, u.y, u.z, u.w};
#pragma unroll
            for (int r = 0; r < 4; ++r) {
                acc[q * 8 + r * 2]     += __uint_as_float(vv[r] << 16);
                acc[q * 8 + r * 2 + 1] += __uint_as_float(vv[r] & 0xffff0000u);
            }
        }
    }

    float scale = nd[node];
    float t1[HID];
#pragma unroll
    for (int j = 0; j < HID; ++j) t1[j] = bc[j];
#pragma unroll 4
    for (int k = 0; k < HID; ++k) {
        float f = acc[k] * scale;
#pragma unroll
        for (int j = 0; j < HID; ++j) t1[j] += f * swc[k * HID + j];
    }
#pragma unroll
    for (int j = 0; j < HID; ++j) t1[j] = elu_f(t1[j]);

    float t2[HID];
#pragma unroll
    for (int j = 0; j < HID; ++j) t2[j] = b[j];
#pragma unroll 4
    for (int k = 0; k < HID; ++k) {
        float f = t1[k];
#pragma unroll
        for (int j = 0; j < HID; ++j) t2[j] += f * sw[k * HID + j];
    }

    float mu = 0.0f;
#pragma unroll
    for (int j = 0; j < HID; ++j) mu += t2[j];
    mu *= (1.0f / HID);
    float var = 0.0f;
#pragma unroll
    for (int j = 0; j < HID; ++j) { float d = t2[j] - mu; var += d * d; }
    var *= (1.0f / HID);
    float rs = rsqrtf(var + LN_EPS);

    float os = ns_out ? ns_out[node] : 1.0f;
#pragma unroll
    for (int j = 0; j < HID; ++j)
        t2[j] = elu_f((t2[j] - mu) * rs * g[j] + be[j]) * os;

    uint words[HID / 2];
#pragma unroll
    for (int q = 0; q < HID / 2; ++q)
        words[q] = f2bf(t2[2 * q]) | (f2bf(t2[2 * q + 1]) << 16);
    uint4* hv = (uint4*)&hout[(size_t)node * HID];
#pragma unroll
    for (int q = 0; q < 4; ++q)
        hv[q] = make_uint4(words[4 * q], words[4 * q + 1], words[4 * q + 2], words[4 * q + 3]);
}

// ---------------- output head + per-graph readout (gid sorted) ----------------
__global__ __launch_bounds__(256) void readout(const ushort* __restrict__ h,
                                               const int* __restrict__ gid,
                                               const float* __restrict__ wout,
                                               const float* __restrict__ bout,
                                               float* __restrict__ out) {
    __shared__ float swout[HID];
    __shared__ float buckets[N_GRAPHS];
    __shared__ int s_gf, s_range;
    int base = blockIdx.x * 256;
    int tid = threadIdx.x;
    int nrows = min(256, N_ATOMS - base);

    if (tid < HID) swout[tid] = wout[tid];
    if (tid == 0) {
        int gf = gid[base];
        int gl = gid[base + nrows - 1];
        s_gf = gf;
        s_range = gl - gf + 1;
    }
    __syncthreads();
    int gf = s_gf, range = s_range;
    for (int i = tid; i < range; i += 256) buckets[i] = 0.0f;
    __syncthreads();

    if (tid < nrows) {
        int node = base + tid;
        const uint4* hv = (const uint4*)&h[(size_t)node * HID];
        float acc = bout[0];
#pragma unroll
        for (int q = 0; q < 4; ++q) {
            uint4 u = hv[q];
            uint vv[4] = {u.x, u.y, u.z, u.w};
#pragma unroll
            for (int r = 0; r < 4; ++r) {
                float lo = __uint_as_float(vv[r] << 16);
                float hi = __uint_as_float(vv[r] & 0xffff0000u);
                acc += lo * swout[q * 8 + r * 2] + hi * swout[q * 8 + r * 2 + 1];
            }
        }
        acc = elu_f(acc);
        atomicAdd(&buckets[gid[node] - gf], acc);
    }
    __syncthreads();
    for (int i = tid; i < range; i += 256) {
        float v = buckets[i];
        if (v != 0.0f) atomicAdd(&out[gf + i], v);
    }
}

extern "C" void kernel_launch(void* const* d_in, const int* in_sizes, int n_in,
                              void* d_out, int out_size, void* d_ws, size_t ws_size,
                              hipStream_t stream) {
    const float* feats = (const float*)d_in[0];
    const int* src = (const int*)d_in[1];
    const int* dst = (const int*)d_in[2];
    const int* gid = (const int*)d_in[3];
    const float* w0  = (const float*)d_in[4];
    const float* b0  = (const float*)d_in[5];
    const float* g0  = (const float*)d_in[6];
    const float* be0 = (const float*)d_in[7];
    const float* wc1 = (const float*)d_in[8];
    const float* bc1 = (const float*)d_in[9];
    const float* w1  = (const float*)d_in[10];
    const float* b1  = (const float*)d_in[11];
    const float* g1  = (const float*)d_in[12];
    const float* be1 = (const float*)d_in[13];
    const float* wc2 = (const float*)d_in[14];
    const float* bc2 = (const float*)d_in[15];
    const float* w2  = (const float*)d_in[16];
    const float* b2  = (const float*)d_in[17];
    const float* g2  = (const float*)d_in[18];
    const float* be2 = (const float*)d_in[19];
    const float* wout = (const float*)d_in[20];
    const float* bout = (const float*)d_in[21];
    float* out = (float*)d_out;

    // workspace layout (~176 MB)
    char* ws = (char*)d_ws;
    ushort* h0  = (ushort*)(ws + 0);           // 64,000,000 B
    ushort* h1  = (ushort*)(ws + 64000000);    // 64,000,000 B
    int* offs   = (int*)(ws + 128000000);      // 4,000,004 B (N+1)
    int* eidx   = (int*)(ws + 132000064);      // 16,000,000 B
    int* rank   = (int*)(ws + 148000064);      // 16,000,000 B
    float* ns   = (float*)(ws + 164000064);    // 4,000,000 B
    float* nd   = (float*)(ws + 168000064);    // 4,000,000 B
    int* deg_o  = (int*)(ws + 172000064);      // 4,000,000 B
    int* deg_i  = (int*)(ws + 176000064);      // 4,000,000 B
    int* bsum   = (int*)(ws + 180000064);      // 4,096 B

    hipMemsetAsync(deg_o, 0, 2 * (size_t)N_ATOMS * sizeof(int), stream);  // deg_o + deg_i
    hipMemsetAsync(out, 0, (size_t)N_GRAPHS * sizeof(float), stream);

    int eb = (N_EDGES + 255) / 256;           // 15625
    int eb4 = (N_EDGES / 4 + 255) / 256;      // 3907
    int nb = (N_ATOMS + 255) / 256;           // 3907

    deg_rank<<<eb4, 256, 0, stream>>>(src, dst, deg_o, deg_i, rank);
    norm_kernel<<<nb, 256, 0, stream>>>(deg_o, deg_i, ns, nd);
    scan_a<<<SCAN_NB, 256, 0, stream>>>(deg_i, offs, bsum);
    scan_b<<<1, 1024, 0, stream>>>(bsum);
    scan_c<<<SCAN_NB, 256, 0, stream>>>(offs, bsum);
    fill_csr<<<eb, 256, 0, stream>>>(src, dst, rank, offs, eidx);

    input_mlp<<<nb, 256, 0, stream>>>(feats, w0, b0, g0, be0, ns, h0);

    conv_node<<<nb, 256, 0, stream>>>(h0, offs, eidx, nd, wc1, bc1, w1, b1, g1, be1, ns, h1);
    conv_node<<<nb, 256, 0, stream>>>(h1, offs, eidx, nd, wc2, bc2, w2, b2, g2, be2, nullptr, h0);

    readout<<<nb, 256, 0, stream>>>(h0, gid, wout, bout, out);
}

// Round 4
// 659.974 us; speedup vs baseline: 6.1467x; 1.4405x over previous
//
#include <hip/hip_runtime.h>
#include <math.h>

#define N_ATOMS 1000000
#define N_EDGES 4000000
#define N_GRAPHS 1024
#define IN_F 64
#define HID 32
#define LN_EPS 1e-5f
#define NB 1024                       // radix buckets (node_id >> 10)
#define PB 512                        // partition blocks
#define CHUNK ((N_EDGES + PB - 1) / PB)   // 7813
#define NBUCK_USED 977                // ceil(1e6 / 1024)

typedef unsigned int uint;
typedef unsigned short ushort;

__device__ __forceinline__ float elu_f(float x) {
    return x > 0.0f ? x : expm1f(x);
}
__device__ __forceinline__ uint f2bf(float x) {   // fp32 -> bf16 bits, RNE
    uint u = __float_as_uint(x);
    return (u + 0x7fffu + ((u >> 16) & 1u)) >> 16;
}

// ------- phase A: per-block LDS histograms of src/dst buckets (no global atomics) -------
__global__ __launch_bounds__(256) void hist2(const int* __restrict__ src,
                                             const int* __restrict__ dst,
                                             int* __restrict__ Hs,
                                             int* __restrict__ Hd) {
    __shared__ int hs[NB], hd[NB];
    int blk = blockIdx.x, tid = threadIdx.x;
    for (int i = tid; i < NB; i += 256) { hs[i] = 0; hd[i] = 0; }
    __syncthreads();
    int e0 = blk * CHUNK, e1 = min(N_EDGES, e0 + CHUNK);
    for (int e = e0 + tid; e < e1; e += 256) {
        atomicAdd(&hs[src[e] >> 10], 1);
        atomicAdd(&hd[dst[e] >> 10], 1);
    }
    __syncthreads();
    for (int i = tid; i < NB; i += 256) {
        Hs[blk * NB + i] = hs[i];
        Hd[blk * NB + i] = hd[i];
    }
}

// ------- phase B1: exclusive scan down each bucket column (over PB blocks) -------
__global__ __launch_bounds__(256) void col_scan(int* __restrict__ H,
                                                int* __restrict__ btot) {
    __shared__ int lds[256];
    int b = blockIdx.x, tid = threadIdx.x;
    int v0 = H[(2 * tid) * NB + b];
    int v1 = H[(2 * tid + 1) * NB + b];
    lds[tid] = v0 + v1;
    __syncthreads();
    for (int off = 1; off < 256; off <<= 1) {
        int t = (tid >= off) ? lds[tid - off] : 0;
        __syncthreads();
        lds[tid] += t;
        __syncthreads();
    }
    int excl = (tid > 0) ? lds[tid - 1] : 0;
    H[(2 * tid) * NB + b] = excl;
    H[(2 * tid + 1) * NB + b] = excl + v0;
    if (tid == 255) btot[b] = excl + v0 + v1;
}

// ------- phase B2: exclusive scan of bucket totals (block 0: dst, block 1: src) -------
__global__ __launch_bounds__(256) void bucket_scan(const int* __restrict__ btot_d,
                                                   int* __restrict__ bbase_d,
                                                   const int* __restrict__ btot_s,
                                                   int* __restrict__ bbase_s) {
    __shared__ int lds[256];
    const int* in = (blockIdx.x == 0) ? btot_d : btot_s;
    int* out = (blockIdx.x == 0) ? bbase_d : bbase_s;
    int tid = threadIdx.x;
    int v[4]; int s = 0;
#pragma unroll
    for (int q = 0; q < 4; ++q) { v[q] = in[tid * 4 + q]; s += v[q]; }
    lds[tid] = s;
    __syncthreads();
    for (int off = 1; off < 256; off <<= 1) {
        int t = (tid >= off) ? lds[tid - off] : 0;
        __syncthreads();
        lds[tid] += t;
        __syncthreads();
    }
    int run = (tid > 0) ? lds[tid - 1] : 0;
#pragma unroll
    for (int q = 0; q < 4; ++q) { out[tid * 4 + q] = run; run += v[q]; }
    if (tid == 255) out[NB] = run;   // == N_EDGES
}

// ------- phase C: scatter edges into dst-buckets as (dst,src) pairs -------
__global__ __launch_bounds__(256) void scatter_dst(const int* __restrict__ src,
                                                   const int* __restrict__ dst,
                                                   const int* __restrict__ Hd,
                                                   const int* __restrict__ bbase_d,
                                                   int2* __restrict__ pedge) {
    __shared__ int cur[NB];
    int blk = blockIdx.x, tid = threadIdx.x;
    for (int i = tid; i < NB; i += 256) cur[i] = bbase_d[i] + Hd[blk * NB + i];
    __syncthreads();
    int e0 = blk * CHUNK, e1 = min(N_EDGES, e0 + CHUNK);
    for (int e = e0 + tid; e < e1; e += 256) {
        int d = dst[e], s = src[e];
        int pos = atomicAdd(&cur[d >> 10], 1);
        pedge[pos] = make_int2(d, s);
    }
}

// ------- phase C': scatter src values into src-buckets -------
__global__ __launch_bounds__(256) void scatter_src(const int* __restrict__ src,
                                                   const int* __restrict__ Hs,
                                                   const int* __restrict__ bbase_s,
                                                   int* __restrict__ psrc) {
    __shared__ int cur[NB];
    int blk = blockIdx.x, tid = threadIdx.x;
    for (int i = tid; i < NB; i += 256) cur[i] = bbase_s[i] + Hs[blk * NB + i];
    __syncthreads();
    int e0 = blk * CHUNK, e1 = min(N_EDGES, e0 + CHUNK);
    for (int e = e0 + tid; e < e1; e += 256) {
        int s = src[e];
        int pos = atomicAdd(&cur[s >> 10], 1);
        psrc[pos] = s;
    }
}

// ------- phase D1: per-bucket CSR build + in-degree norm (LDS only) -------
__global__ __launch_bounds__(256) void bucket_csr(const int2* __restrict__ pedge,
                                                  const int* __restrict__ bbase_d,
                                                  int* __restrict__ eidx,
                                                  int* __restrict__ offs,
                                                  float* __restrict__ nd) {
    __shared__ int deg[NB];
    __shared__ int cur[NB];
    __shared__ int lds[256];
    int b = blockIdx.x, tid = threadIdx.x;
    int nbase = b << 10;
    if (nbase > N_ATOMS) return;
    int ebase = bbase_d[b], eend = bbase_d[b + 1];
    for (int i = tid; i < NB; i += 256) deg[i] = 0;
    __syncthreads();
    for (int i = ebase + tid; i < eend; i += 256)
        atomicAdd(&deg[pedge[i].x & (NB - 1)], 1);
    __syncthreads();
    int v[4]; int s = 0;
#pragma unroll
    for (int q = 0; q < 4; ++q) { v[q] = deg[tid * 4 + q]; s += v[q]; }
    lds[tid] = s;
    __syncthreads();
    for (int off = 1; off < 256; off <<= 1) {
        int t = (tid >= off) ? lds[tid - off] : 0;
        __syncthreads();
        lds[tid] += t;
        __syncthreads();
    }
    int run = (tid > 0) ? lds[tid - 1] : 0;
#pragma unroll
    for (int q = 0; q < 4; ++q) {
        int l = tid * 4 + q;
        cur[l] = run;
        int node = nbase + l;
        if (node <= N_ATOMS) {
            offs[node] = ebase + run;           // node==N lands here with run==bucket total
            if (node < N_ATOMS) nd[node] = v[q] > 0 ? rsqrtf((float)v[q]) : 0.0f;
        }
        run += v[q];
    }
    __syncthreads();
    for (int i = ebase + tid; i < eend; i += 256) {
        int2 ed = pedge[i];
        int p = atomicAdd(&cur[ed.x & (NB - 1)], 1);
        eidx[ebase + p] = ed.y;
    }
}

// ------- phase D2: per-bucket out-degree norm -------
__global__ __launch_bounds__(256) void bucket_ns(const int* __restrict__ psrc,
                                                 const int* __restrict__ bbase_s,
                                                 float* __restrict__ ns) {
    __shared__ int deg[NB];
    int b = blockIdx.x, tid = threadIdx.x;
    int nbase = b << 10;
    if (nbase >= N_ATOMS) return;
    int ebase = bbase_s[b], eend = bbase_s[b + 1];
    for (int i = tid; i < NB; i += 256) deg[i] = 0;
    __syncthreads();
    for (int i = ebase + tid; i < eend; i += 256)
        atomicAdd(&deg[psrc[i] & (NB - 1)], 1);
    __syncthreads();
    for (int l = tid; l < NB; l += 256) {
        int node = nbase + l;
        if (node < N_ATOMS) {
            int c = deg[l];
            ns[node] = c > 0 ? rsqrtf((float)c) : 0.0f;
        }
    }
}

// ------- input MLP: Linear(64->32) + LN + ELU, output prescaled by ns -> bf16 -------
__global__ __launch_bounds__(256) void input_mlp(const float* __restrict__ feats,
                                                 const float* __restrict__ w0,
                                                 const float* __restrict__ b0,
                                                 const float* __restrict__ g0,
                                                 const float* __restrict__ be0,
                                                 const float* __restrict__ ns,
                                                 ushort* __restrict__ hs) {
    __shared__ float sf[256 * 65];
    __shared__ float sw[IN_F * HID];
    int base = blockIdx.x * 256;
    int tid = threadIdx.x;

    for (int i = tid; i < IN_F * HID; i += 256) sw[i] = w0[i];

    int nrows = min(256, N_ATOMS - base);
    for (int i = tid; i < nrows * IN_F; i += 256) {
        int r = i >> 6, c = i & 63;
        sf[r * 65 + c] = feats[(size_t)base * IN_F + i];
    }
    __syncthreads();
    if (tid >= nrows) return;

    float acc[HID];
#pragma unroll
    for (int j = 0; j < HID; ++j) acc[j] = b0[j];

    const float* frow = &sf[tid * 65];
#pragma unroll 4
    for (int k = 0; k < IN_F; ++k) {
        float f = frow[k];
#pragma unroll
        for (int j = 0; j < HID; ++j) acc[j] += f * sw[k * HID + j];
    }

    float mu = 0.0f;
#pragma unroll
    for (int j = 0; j < HID; ++j) mu += acc[j];
    mu *= (1.0f / HID);
    float var = 0.0f;
#pragma unroll
    for (int j = 0; j < HID; ++j) { float d = acc[j] - mu; var += d * d; }
    var *= (1.0f / HID);
    float rs = rsqrtf(var + LN_EPS);

    float os = ns[base + tid];
#pragma unroll
    for (int j = 0; j < HID; ++j)
        acc[j] = elu_f((acc[j] - mu) * rs * g0[j] + be0[j]) * os;

    uint words[HID / 2];
#pragma unroll
    for (int q = 0; q < HID / 2; ++q)
        words[q] = f2bf(acc[2 * q]) | (f2bf(acc[2 * q + 1]) << 16);
    uint4* hv = (uint4*)&hs[(size_t)(base + tid) * HID];
#pragma unroll
    for (int q = 0; q < 4; ++q)
        hv[q] = make_uint4(words[4 * q], words[4 * q + 1], words[4 * q + 2], words[4 * q + 3]);
}

// ---- fused GraphConv + node MLP: pull row-sum (inputs pre-scaled by ns) ----
__global__ __launch_bounds__(256) void conv_node(const ushort* __restrict__ hin,
                                                 const int* __restrict__ offs,
                                                 const int* __restrict__ eidx,
                                                 const float* __restrict__ nd,
                                                 const float* __restrict__ wc,
                                                 const float* __restrict__ bc,
                                                 const float* __restrict__ w,
                                                 const float* __restrict__ b,
                                                 const float* __restrict__ g,
                                                 const float* __restrict__ be,
                                                 const float* __restrict__ ns_out,
                                                 ushort* __restrict__ hout) {
    __shared__ float swc[HID * HID];
    __shared__ float sw[HID * HID];
    int tid = threadIdx.x;
    for (int i = tid; i < HID * HID; i += 256) { swc[i] = wc[i]; sw[i] = w[i]; }
    __syncthreads();

    int node = blockIdx.x * 256 + tid;
    if (node >= N_ATOMS) return;

    int s0 = offs[node], s1 = offs[node + 1];
    float acc[HID];
#pragma unroll
    for (int j = 0; j < HID; ++j) acc[j] = 0.0f;

    for (int i = s0; i < s1; ++i) {
        int s = eidx[i];
        const uint4* hr = (const uint4*)(hin + (size_t)s * HID);
#pragma unroll
        for (int q = 0; q < 4; ++q) {
            uint4 u = hr[q];
            uint vv[4] = {u.x, u.y, u.z, u.w};
#pragma unroll
            for (int r = 0; r < 4; ++r) {
                acc[q * 8 + r * 2]     += __uint_as_float(vv[r] << 16);
                acc[q * 8 + r * 2 + 1] += __uint_as_float(vv[r] & 0xffff0000u);
            }
        }
    }

    float scale = nd[node];
    float t1[HID];
#pragma unroll
    for (int j = 0; j < HID; ++j) t1[j] = bc[j];
#pragma unroll 4
    for (int k = 0; k < HID; ++k) {
        float f = acc[k] * scale;
#pragma unroll
        for (int j = 0; j < HID; ++j) t1[j] += f * swc[k * HID + j];
    }
#pragma unroll
    for (int j = 0; j < HID; ++j) t1[j] = elu_f(t1[j]);

    float t2[HID];
#pragma unroll
    for (int j = 0; j < HID; ++j) t2[j] = b[j];
#pragma unroll 4
    for (int k = 0; k < HID; ++k) {
        float f = t1[k];
#pragma unroll
        for (int j = 0; j < HID; ++j) t2[j] += f * sw[k * HID + j];
    }

    float mu = 0.0f;
#pragma unroll
    for (int j = 0; j < HID; ++j) mu += t2[j];
    mu *= (1.0f / HID);
    float var = 0.0f;
#pragma unroll
    for (int j = 0; j < HID; ++j) { float d = t2[j] - mu; var += d * d; }
    var *= (1.0f / HID);
    float rs = rsqrtf(var + LN_EPS);

    float os = ns_out ? ns_out[node] : 1.0f;
#pragma unroll
    for (int j = 0; j < HID; ++j)
        t2[j] = elu_f((t2[j] - mu) * rs * g[j] + be[j]) * os;

    uint words[HID / 2];
#pragma unroll
    for (int q = 0; q < HID / 2; ++q)
        words[q] = f2bf(t2[2 * q]) | (f2bf(t2[2 * q + 1]) << 16);
    uint4* hv = (uint4*)&hout[(size_t)node * HID];
#pragma unroll
    for (int q = 0; q < 4; ++q)
        hv[q] = make_uint4(words[4 * q], words[4 * q + 1], words[4 * q + 2], words[4 * q + 3]);
}

// ---------------- output head + per-graph readout (gid sorted) ----------------
__global__ __launch_bounds__(256) void readout(const ushort* __restrict__ h,
                                               const int* __restrict__ gid,
                                               const float* __restrict__ wout,
                                               const float* __restrict__ bout,
                                               float* __restrict__ out) {
    __shared__ float swout[HID];
    __shared__ float buckets[N_GRAPHS];
    __shared__ int s_gf, s_range;
    int base = blockIdx.x * 256;
    int tid = threadIdx.x;
    int nrows = min(256, N_ATOMS - base);

    if (tid < HID) swout[tid] = wout[tid];
    if (tid == 0) {
        int gf = gid[base];
        int gl = gid[base + nrows - 1];
        s_gf = gf;
        s_range = gl - gf + 1;
    }
    __syncthreads();
    int gf = s_gf, range = s_range;
    for (int i = tid; i < range; i += 256) buckets[i] = 0.0f;
    __syncthreads();

    if (tid < nrows) {
        int node = base + tid;
        const uint4* hv = (const uint4*)&h[(size_t)node * HID];
        float acc = bout[0];
#pragma unroll
        for (int q = 0; q < 4; ++q) {
            uint4 u = hv[q];
            uint vv[4] = {u.x, u.y, u.z, u.w};
#pragma unroll
            for (int r = 0; r < 4; ++r) {
                float lo = __uint_as_float(vv[r] << 16);
                float hi = __uint_as_float(vv[r] & 0xffff0000u);
                acc += lo * swout[q * 8 + r * 2] + hi * swout[q * 8 + r * 2 + 1];
            }
        }
        acc = elu_f(acc);
        atomicAdd(&buckets[gid[node] - gf], acc);
    }
    __syncthreads();
    for (int i = tid; i < range; i += 256) {
        float v = buckets[i];
        if (v != 0.0f) atomicAdd(&out[gf + i], v);
    }
}

extern "C" void kernel_launch(void* const* d_in, const int* in_sizes, int n_in,
                              void* d_out, int out_size, void* d_ws, size_t ws_size,
                              hipStream_t stream) {
    const float* feats = (const float*)d_in[0];
    const int* src = (const int*)d_in[1];
    const int* dst = (const int*)d_in[2];
    const int* gid = (const int*)d_in[3];
    const float* w0  = (const float*)d_in[4];
    const float* b0  = (const float*)d_in[5];
    const float* g0  = (const float*)d_in[6];
    const float* be0 = (const float*)d_in[7];
    const float* wc1 = (const float*)d_in[8];
    const float* bc1 = (const float*)d_in[9];
    const float* w1  = (const float*)d_in[10];
    const float* b1  = (const float*)d_in[11];
    const float* g1  = (const float*)d_in[12];
    const float* be1 = (const float*)d_in[13];
    const float* wc2 = (const float*)d_in[14];
    const float* bc2 = (const float*)d_in[15];
    const float* w2  = (const float*)d_in[16];
    const float* b2  = (const float*)d_in[17];
    const float* g2  = (const float*)d_in[18];
    const float* be2 = (const float*)d_in[19];
    const float* wout = (const float*)d_in[20];
    const float* bout = (const float*)d_in[21];
    float* out = (float*)d_out;

    // workspace layout (~200 MB)
    char* ws = (char*)d_ws;
    ushort* h0    = (ushort*)(ws + 0);             // 64,000,000
    ushort* h1    = (ushort*)(ws + 64000000);      // 64,000,000
    int* offs     = (int*)(ws + 128000000);        // 4,000,004  (N+1)
    int* eidx     = (int*)(ws + 132000064);        // 16,000,000
    int2* pedge   = (int2*)(ws + 148000064);       // 32,000,000 (8B aligned)
    int* psrc     = (int*)(ws + 180000064);        // 16,000,000
    int* Hd       = (int*)(ws + 196000064);        // 2,097,152
    int* Hs       = (int*)(ws + 198100000);        // 2,097,152
    int* btot_d   = (int*)(ws + 200200000);        // 4,096
    int* btot_s   = (int*)(ws + 200204096);        // 4,096
    int* bbase_d  = (int*)(ws + 200208192);        // 4,100 (NB+1)
    int* bbase_s  = (int*)(ws + 200212296);        // 4,100
    float* ns     = (float*)(ws + 200216396);      // 4,000,000
    float* nd     = (float*)(ws + 204216396);      // 4,000,000

    hipMemsetAsync(out, 0, (size_t)N_GRAPHS * sizeof(float), stream);

    int nb = (N_ATOMS + 255) / 256;   // 3907

    hist2<<<PB, 256, 0, stream>>>(src, dst, Hs, Hd);
    col_scan<<<NB, 256, 0, stream>>>(Hd, btot_d);
    col_scan<<<NB, 256, 0, stream>>>(Hs, btot_s);
    bucket_scan<<<2, 256, 0, stream>>>(btot_d, bbase_d, btot_s, bbase_s);
    scatter_dst<<<PB, 256, 0, stream>>>(src, dst, Hd, bbase_d, pedge);
    scatter_src<<<PB, 256, 0, stream>>>(src, Hs, bbase_s, psrc);
    bucket_csr<<<NBUCK_USED, 256, 0, stream>>>(pedge, bbase_d, eidx, offs, nd);
    bucket_ns<<<NBUCK_USED, 256, 0, stream>>>(psrc, bbase_s, ns);

    input_mlp<<<nb, 256, 0, stream>>>(feats, w0, b0, g0, be0, ns, h0);

    conv_node<<<nb, 256, 0, stream>>>(h0, offs, eidx, nd, wc1, bc1, w1, b1, g1, be1, ns, h1);
    conv_node<<<nb, 256, 0, stream>>>(h1, offs, eidx, nd, wc2, bc2, w2, b2, g2, be2, nullptr, h0);

    readout<<<nb, 256, 0, stream>>>(h0, gid, wout, bout, out);
}